// Round 8
// baseline (614.011 us; speedup 1.0000x reference)
//
#include <hip/hip_runtime.h>
#include <hip/hip_bf16.h>
#include <math.h>

#define CAP 2048
#define PRNG_PARTITIONABLE 1

typedef __attribute__((ext_vector_type(8))) short bf16x8;
typedef __attribute__((ext_vector_type(4))) float f32x4;
typedef __attribute__((ext_vector_type(4))) unsigned int u32x4;

union B8U4 { u32x4 u; bf16x8 b; };

// ---------- helpers ----------
__device__ __forceinline__ unsigned int f2ord(float x) {
  unsigned int u = __float_as_uint(x);
  return (u & 0x80000000u) ? ~u : (u | 0x80000000u);
}

__device__ __forceinline__ unsigned int rotl_u32(unsigned int x, int r) {
  return (x << r) | (x >> (32 - r));
}

__device__ float gumbel_at(unsigned int flat, unsigned int half_n) {
  const unsigned int ks0 = 0u;
  const unsigned int ks1 = 42u;
  const unsigned int ks2 = 0x1BD11BDAu ^ ks0 ^ ks1;
  unsigned int x0, x1;
#if PRNG_PARTITIONABLE
  x0 = 0u;
  x1 = flat;
#else
  unsigned int cnt = (flat < half_n) ? flat : (flat - half_n);
  x0 = cnt; x1 = cnt + half_n;
#endif
  x0 += ks0; x1 += ks1;
#define TF_R(r) { x0 += x1; x1 = rotl_u32(x1, r); x1 ^= x0; }
  TF_R(13) TF_R(15) TF_R(26) TF_R(6)
  x0 += ks1; x1 += ks2 + 1u;
  TF_R(17) TF_R(29) TF_R(16) TF_R(24)
  x0 += ks2; x1 += ks0 + 2u;
  TF_R(13) TF_R(15) TF_R(26) TF_R(6)
  x0 += ks0; x1 += ks1 + 3u;
  TF_R(17) TF_R(29) TF_R(16) TF_R(24)
  x0 += ks1; x1 += ks2 + 4u;
  TF_R(13) TF_R(15) TF_R(26) TF_R(6)
  x0 += ks2; x1 += ks0 + 5u;
#undef TF_R
#if PRNG_PARTITIONABLE
  unsigned int bits = x0 ^ x1;
#else
  unsigned int bits = (flat < half_n) ? x0 : x1;
#endif
  float f = __uint_as_float(0x3f800000u | (bits >> 9)) - 1.0f;
  float u = fmaxf(1e-20f, f + 1e-20f);
  return -logf(-logf(u));
}

__device__ __forceinline__ unsigned short f32_to_bf16_rne(float x) {
  unsigned int u = __float_as_uint(x);
  unsigned int r = u + 0x7fffu + ((u >> 16) & 1u);
  return (unsigned short)(r >> 16);
}
__device__ __forceinline__ float bf16u_to_f32(unsigned short h) {
  return __uint_as_float(((unsigned int)h) << 16);
}

struct HL { unsigned int h, l; };
__device__ __forceinline__ HL cvt_pair(float a, float b) {
  float2 xf = make_float2(a, b);
  __hip_bfloat162 hh = __float22bfloat162_rn(xf);
  float2 hf = __bfloat1622float2(hh);
  __hip_bfloat162 ll = __float22bfloat162_rn(make_float2(a - hf.x, b - hf.y));
  HL r;
  __builtin_memcpy(&r.h, &hh, 4);
  __builtin_memcpy(&r.l, &ll, 4);
  return r;
}

__device__ __forceinline__ f32x4 mfma16(bf16x8 a, bf16x8 b, f32x4 c) {
  return __builtin_amdgcn_mfma_f32_16x16x32_bf16(a, b, c, 0, 0, 0);
}

// ---------- K0: gather last-token rows + split to bf16 hi/lo ----------
__global__ void gather_split(const float* __restrict__ hidden, const int* __restrict__ lti,
                             unsigned short* __restrict__ Ah, unsigned short* __restrict__ Al,
                             int D) {
  int b = blockIdx.x;
  const float* src = hidden + (size_t)lti[b] * D;
  for (int i = threadIdx.x; i < D; i += blockDim.x) {
    float x = src[i];
    unsigned short h = f32_to_bf16_rne(x);
    float r = x - bf16u_to_f32(h);
    Ah[(size_t)b * D + i] = h;
    Al[(size_t)b * D + i] = f32_to_bf16_rne(r);
  }
}

// ---------- K1: logits = A @ E^T via bf16x3 MFMA — ALL-REGISTER, no LDS ----
// BM=64, BN=128. 4 waves; wave w owns n in [w*32, w*32+32) (2 nf tiles).
// B fragment loaded global->reg: lanes {l,l+16,l+32,l+48} share a row, each
// takes its og*32B slice -> wave covers 16 rows x contiguous bytes (coalesced).
// A fragment likewise (16 rows x 64B per instr, L2-hot). No barriers at all.
#define BN 128
__global__ __launch_bounds__(256, 2) void gemm_mfma(
    const unsigned short* __restrict__ Ahg, const unsigned short* __restrict__ Alg,
    const float* __restrict__ E, float* __restrict__ outL, int D, int V) {
  const int t = threadIdx.x;
  const int lane = t & 63;
  const int wv = t >> 6;
  const int li = lane & 15, og = lane >> 4;
  const long n0 = (long)blockIdx.x * BN;

  f32x4 acc[4][2];
#pragma unroll
  for (int i = 0; i < 4; ++i)
#pragma unroll
    for (int j = 0; j < 2; ++j) acc[i][j] = (f32x4){0.f, 0.f, 0.f, 0.f};

  // per-lane row base pointers (k-offset og*8 elements)
  const float* pb0 = E + (size_t)(n0 + wv * 32 + li) * D + og * 8;
  const float* pb1 = E + (size_t)(n0 + wv * 32 + 16 + li) * D + og * 8;
  const unsigned short* pah = Ahg + (size_t)li * D + og * 8;
  const unsigned short* pal = Alg + (size_t)li * D + og * 8;
  const size_t mstr = (size_t)16 * D;  // row stride between mf tiles

#define LOADB(dst, k) {                       \
    dst[0] = *(const f32x4*)(pb0 + (k));      \
    dst[1] = *(const f32x4*)(pb0 + (k) + 4);  \
    dst[2] = *(const f32x4*)(pb1 + (k));      \
    dst[3] = *(const f32x4*)(pb1 + (k) + 4);  \
  }
#define LOADA(ah, al, k) {                                    \
    _Pragma("unroll")                                         \
    for (int mf = 0; mf < 4; ++mf) {                          \
      ah[mf] = *(const bf16x8*)(pah + mf * mstr + (k));       \
      al[mf] = *(const bf16x8*)(pal + mf * mstr + (k));       \
    }                                                         \
  }
#define CVT_MFMA(bv, ah, al) {                                \
    bf16x8 bh[2], bl[2];                                      \
    _Pragma("unroll")                                         \
    for (int nf = 0; nf < 2; ++nf) {                          \
      f32x4 v0 = bv[2 * nf], v1 = bv[2 * nf + 1];             \
      HL q0 = cvt_pair(v0.x, v0.y);                           \
      HL q1 = cvt_pair(v0.z, v0.w);                           \
      HL q2 = cvt_pair(v1.x, v1.y);                           \
      HL q3 = cvt_pair(v1.z, v1.w);                           \
      B8U4 hb, lb;                                            \
      hb.u = (u32x4){q0.h, q1.h, q2.h, q3.h};                 \
      lb.u = (u32x4){q0.l, q1.l, q2.l, q3.l};                 \
      bh[nf] = hb.b;                                          \
      bl[nf] = lb.b;                                          \
    }                                                         \
    __builtin_amdgcn_s_setprio(1);                            \
    _Pragma("unroll")                                         \
    for (int mf = 0; mf < 4; ++mf)                            \
      _Pragma("unroll")                                       \
      for (int nf = 0; nf < 2; ++nf) {                        \
        acc[mf][nf] = mfma16(ah[mf], bh[nf], acc[mf][nf]);    \
        acc[mf][nf] = mfma16(ah[mf], bl[nf], acc[mf][nf]);    \
        acc[mf][nf] = mfma16(al[mf], bh[nf], acc[mf][nf]);    \
      }                                                       \
    __builtin_amdgcn_s_setprio(0);                            \
  }

  f32x4 bX[4], bY[4];
  bf16x8 ahX[4], alX[4], ahY[4], alY[4];

  LOADB(bX, 0);
  LOADA(ahX, alX, 0);
#pragma unroll 1
  for (int k = 0; k < D; k += 64) {
    LOADB(bY, k + 32);
    LOADA(ahY, alY, k + 32);
    CVT_MFMA(bX, ahX, alX);
    if (k + 64 < D) {
      LOADB(bX, k + 64);
      LOADA(ahX, alX, k + 64);
    }
    CVT_MFMA(bY, ahY, alY);
  }
#undef LOADB
#undef LOADA
#undef CVT_MFMA

  // epilogue: D layout col=lane&15, row=(lane>>4)*4+reg
#pragma unroll
  for (int mf = 0; mf < 4; ++mf)
#pragma unroll
    for (int nf = 0; nf < 2; ++nf) {
      long v = n0 + wv * 32 + nf * 16 + li;
      int rbase = mf * 16 + (og << 2);
#pragma unroll
      for (int reg = 0; reg < 4; ++reg)
        outL[(size_t)(rbase + reg) * V + v] = acc[mf][nf][reg];
    }
}

// ---------- K2a: per-chunk top-byte histogram (8 blocks/row) ----------
__global__ __launch_bounds__(256) void hist_k(
    const float* __restrict__ logits, unsigned int* __restrict__ ghist, int V) {
  const int b = blockIdx.x >> 3, c = blockIdx.x & 7;
  const int CH = V >> 3;
  const float* row = logits + (size_t)b * V;
  __shared__ unsigned int lh[4][256];
  const int tid = threadIdx.x, wv = tid >> 6;
  for (int i = tid; i < 1024; i += 256) ((unsigned int*)lh)[i] = 0u;
  __syncthreads();
  const int base = c * CH;
  for (int i = base + tid * 4; i < base + CH; i += 1024) {
    f32x4 v = *(const f32x4*)(row + i);
    atomicAdd(&lh[wv][f2ord(v.x) >> 24], 1u);
    atomicAdd(&lh[wv][f2ord(v.y) >> 24], 1u);
    atomicAdd(&lh[wv][f2ord(v.z) >> 24], 1u);
    atomicAdd(&lh[wv][f2ord(v.w) >> 24], 1u);
  }
  __syncthreads();
  if (tid < 256) {
    unsigned int s = lh[0][tid] + lh[1][tid] + lh[2][tid] + lh[3][tid];
    if (s) atomicAdd(&ghist[b * 256 + tid], s);
  }
}

// ---------- K2b: per-row threshold (rare in-block 2nd-byte refine) ----------
__global__ __launch_bounds__(256) void thresh_k(
    const float* __restrict__ logits, const unsigned int* __restrict__ ghist,
    const int* __restrict__ top_ks, unsigned int* __restrict__ tau16, int V) {
  const int b = blockIdx.x, tid = threadIdx.x;
  __shared__ unsigned int h[256];
  __shared__ unsigned int h2[4][256];
  __shared__ int s_bin, s_need, s_refine;
  if (tid < 256) h[tid] = ghist[b * 256 + tid];
  __syncthreads();
  if (tid == 0) {
    int k = top_ks[b];
    if (k < 1) k = 1;
    if (k > V) k = V;
    unsigned int run = 0;
    int bin = 255;
    for (; bin >= 0; --bin) {
      unsigned int hh = h[bin];
      if (run + hh >= (unsigned int)k) break;
      run += hh;
    }
    if (bin < 0) bin = 0;
    s_bin = bin;
    s_need = top_ks[b] < 1 ? 1 : (top_ks[b] > V ? V : top_ks[b]);
    s_need -= (int)run;
    s_refine = (run + h[bin] > (unsigned int)CAP) ? 1 : 0;
    if (!s_refine) tau16[b] = ((unsigned int)bin) << 8;
  }
  __syncthreads();
  if (!s_refine) return;

  const int wv = tid >> 6;
  for (int i = tid; i < 1024; i += 256) ((unsigned int*)h2)[i] = 0u;
  __syncthreads();
  const unsigned int binq = (unsigned int)s_bin;
  const float* row = logits + (size_t)b * V;
  for (int i = tid * 4; i < V; i += 1024) {
    f32x4 v = *(const f32x4*)(row + i);
#pragma unroll
    for (int e = 0; e < 4; ++e) {
      unsigned int u = f2ord(v[e]);
      if ((u >> 24) == binq) atomicAdd(&h2[wv][(u >> 16) & 255u], 1u);
    }
  }
  __syncthreads();
  if (tid == 0) {
    int need = s_need;
    unsigned int run = 0;
    int sub = 255;
    for (; sub >= 0; --sub) {
      unsigned int hh = h2[0][sub] + h2[1][sub] + h2[2][sub] + h2[3][sub];
      if (run + hh >= (unsigned int)need) break;
      run += hh;
    }
    if (sub < 0) sub = 0;
    tau16[b] = (binq << 8) | (unsigned int)sub;
  }
}

// ---------- K2c: gather candidates + zero chunk (8 blocks/row) ----------
__global__ __launch_bounds__(256) void gather_k(
    float* __restrict__ logits, const unsigned int* __restrict__ tau16,
    float* __restrict__ cvals, int* __restrict__ cidx, int* __restrict__ ccnt, int V) {
  const int b = blockIdx.x >> 3, c = blockIdx.x & 7;
  const int CH = V >> 3;
  float* row = logits + (size_t)b * V;
  __shared__ float bv[CAP];
  __shared__ int bi[CAP];
  __shared__ int s_c, s_base;
  const int tid = threadIdx.x;
  if (tid == 0) s_c = 0;
  __syncthreads();
  const unsigned int tau = tau16[b];
  const int base = c * CH;
  const f32x4 z = (f32x4){0.f, 0.f, 0.f, 0.f};
  for (int i = base + tid * 4; i < base + CH; i += 1024) {
    f32x4 v = *(const f32x4*)(row + i);
#pragma unroll
    for (int e = 0; e < 4; ++e) {
      float x = v[e];
      if ((f2ord(x) >> 16) >= tau) {
        int p = atomicAdd(&s_c, 1);
        if (p < CAP) { bv[p] = x; bi[p] = i + e; }
      }
    }
    *(f32x4*)(row + i) = z;  // zero for probs scatter
  }
  __syncthreads();
  int cnt = s_c;
  if (cnt > CAP) cnt = CAP;
  if (tid == 0) s_base = atomicAdd(ccnt + b, cnt);
  __syncthreads();
  const int gb = s_base;
  for (int i = tid; i < cnt; i += 256) {
    int p = gb + i;
    if (p < CAP) {
      cvals[(size_t)b * CAP + p] = bv[i];
      cidx[(size_t)b * CAP + p] = bi[i];
    }
  }
}

// ---------- K3: sort candidates, top-k/top-p, scatter, gumbel ----------
__global__ __launch_bounds__(1024) void finalize_k(
    const float* __restrict__ cvals, const int* __restrict__ cidx,
    const int* __restrict__ ccnt, const int* __restrict__ top_ks,
    const float* __restrict__ temps, const float* __restrict__ top_ps,
    float* __restrict__ out, int probs_base, int V, unsigned int half_n) {
  const int b = blockIdx.x, tid = threadIdx.x;
  __shared__ float vals[CAP];
  __shared__ int idxs[CAP];
  __shared__ float ex[1024];
  __shared__ float pr[1024];
  __shared__ float rsc[1024];
  __shared__ int rid[1024];
  __shared__ float s_S, s_S2;
  __shared__ int s_m;

  int cnt = ccnt[b];
  if (cnt > CAP) cnt = CAP;
  int k = top_ks[b];
  if (k < 1) k = 1;
  if (k > V) k = V;
  int K = (k < cnt) ? k : cnt;
  if (K > 1024) K = 1024;

  for (int i = tid; i < CAP; i += 1024) {
    if (i < cnt) { vals[i] = cvals[(size_t)b * CAP + i]; idxs[i] = cidx[(size_t)b * CAP + i]; }
    else         { vals[i] = -INFINITY;                  idxs[i] = 0x7fffffff; }
  }
  __syncthreads();

  // bitonic sort: (val desc, idx asc) == stable argsort(-logits)
  for (int size = 2; size <= CAP; size <<= 1) {
    for (int stride = size >> 1; stride > 0; stride >>= 1) {
      for (int i = tid; i < CAP; i += 1024) {
        int j = i ^ stride;
        if (j > i) {
          float vi = vals[i], vj = vals[j];
          int ii = idxs[i], ij = idxs[j];
          bool iBeforeJ = (vi > vj) || (vi == vj && ii < ij);
          bool up = ((i & size) == 0);
          if (up ? !iBeforeJ : iBeforeJ) {
            vals[i] = vj; idxs[i] = ij; vals[j] = vi; idxs[j] = ii;
          }
        }
      }
      __syncthreads();
    }
  }

  const float t = temps[b];
  const float tt = (t < 1e-5f) ? 1.0f : t;
  const float l0 = vals[0] / tt;
  for (int i = tid; i < K; i += 1024) ex[i] = expf(vals[i] / tt - l0);
  __syncthreads();

  if (tid == 0) {
    float S = 0.f;
    for (int i = 0; i < K; ++i) S += ex[i];
    s_S = S;
  }
  __syncthreads();
  const float S = s_S;
  for (int i = tid; i < K; i += 1024) pr[i] = ex[i] / S;
  __syncthreads();

  if (tid == 0) {
    float p = top_ps[b];
    int m;
    if (p >= 1.0f - 1e-5f) m = K;
    else {
      m = 1;
      float cum = pr[0];
      for (int i = 1; i < K; ++i) {
        cum += pr[i];
        if (cum <= p) m++; else break;
      }
    }
    s_m = m;
  }
  __syncthreads();
  const int m = s_m;

  {
    float loc = 0.f;
    for (int i = tid; i < m; i += 1024) loc += ex[i];
    rsc[tid] = loc;
    __syncthreads();
    for (int s = 512; s > 0; s >>= 1) {
      if (tid < s) rsc[tid] += rsc[tid + s];
      __syncthreads();
    }
    if (tid == 0) s_S2 = rsc[0];
    __syncthreads();
  }
  const float S2 = s_S2;

  for (int i = tid; i < m; i += 1024)
    out[(size_t)probs_base + (size_t)b * V + idxs[i]] = ex[i] / S2;

  float best = -INFINITY;
  int bestV = 0x7fffffff;
  for (int i = tid; i < m; i += 1024) {
    int vv = idxs[i];
    unsigned int flat = (unsigned int)b * (unsigned int)V + (unsigned int)vv;
    float g = gumbel_at(flat, half_n);
    float sc = vals[i] / tt + g;
    if (sc > best || (sc == best && vv < bestV)) { best = sc; bestV = vv; }
  }
  rsc[tid] = best; rid[tid] = bestV;
  __syncthreads();
  for (int s = 512; s > 0; s >>= 1) {
    if (tid < s) {
      float o = rsc[tid + s]; int oi = rid[tid + s];
      if (o > rsc[tid] || (o == rsc[tid] && oi < rid[tid])) { rsc[tid] = o; rid[tid] = oi; }
    }
    __syncthreads();
  }
  if (tid == 0) {
    int token = (t < 1e-5f) ? idxs[0] : rid[0];
    if (token < 0 || token >= V) token = 0;
    out[b] = (float)token;
  }
}

// ---------- launch ----------
extern "C" void kernel_launch(void* const* d_in, const int* in_sizes, int n_in,
                              void* d_out, int out_size, void* d_ws, size_t ws_size,
                              hipStream_t stream) {
  const float* hidden = (const float*)d_in[0];
  const float* emb    = (const float*)d_in[1];
  const int*   lti    = (const int*)d_in[2];
  const float* temps  = (const float*)d_in[3];
  const float* tops   = (const float*)d_in[4];
  const int*   topks  = (const int*)d_in[5];

  const int B = in_sizes[2];
  const int V = (int)(((long long)out_size - B) / B);
  const int D = in_sizes[1] / V;
  const int probs_base = out_size - B * V;  // = B
  const unsigned int half_n = (unsigned int)(((long long)B * V) / 2);

  float* out = (float*)d_out;

  char* ws = (char*)d_ws;
  size_t off = 0;
  unsigned short* Ah = (unsigned short*)(ws + off); off += (size_t)B * D * sizeof(unsigned short);
  unsigned short* Al = (unsigned short*)(ws + off); off += (size_t)B * D * sizeof(unsigned short);
  float* cvals = (float*)(ws + off); off += (size_t)B * CAP * sizeof(float);
  int* cidx = (int*)(ws + off);      off += (size_t)B * CAP * sizeof(int);
  // zeroed region: ccnt | ghist | tau16 (contiguous, one memsetAsync)
  char* zbase = ws + off;
  int* ccnt = (int*)(ws + off);              off += (size_t)B * sizeof(int);
  unsigned int* ghist = (unsigned int*)(ws + off); off += (size_t)B * 256 * sizeof(unsigned int);
  unsigned int* tau16 = (unsigned int*)(ws + off); off += (size_t)B * sizeof(unsigned int);
  const size_t zbytes = (size_t)(B + B * 256 + B) * sizeof(unsigned int);
  (void)ws_size; (void)n_in;

  float* logits = out + probs_base;

  hipLaunchKernelGGL(gather_split, dim3(B), dim3(256), 0, stream, hidden, lti, Ah, Al, D);
  hipMemsetAsync(zbase, 0, zbytes, stream);
  hipLaunchKernelGGL(gemm_mfma, dim3(V / BN), dim3(256), 0, stream, Ah, Al, emb, logits, D, V);
  hipLaunchKernelGGL(hist_k, dim3(8 * B), dim3(256), 0, stream, logits, ghist, V);
  hipLaunchKernelGGL(thresh_k, dim3(B), dim3(256), 0, stream, logits, ghist, topks, tau16, V);
  hipLaunchKernelGGL(gather_k, dim3(8 * B), dim3(256), 0, stream, logits, tau16, cvals, cidx, ccnt, V);
  hipLaunchKernelGGL(finalize_k, dim3(B), dim3(1024), 0, stream, cvals, cidx, ccnt,
                     topks, temps, tops, out, probs_base, V, half_n);
}